// Round 6
// baseline (161.567 us; speedup 1.0000x reference)
//
#include <hip/hip_runtime.h>
#include <hip/hip_bf16.h>

#define TROWS 1048576
#define RPB   512                    // rows per block = 2 chunks of 256
#define NBLK  (TROWS / RPB)          // 2048
#define LSTRIDE 36                   // LDS row stride in shorts (72 B)

typedef float f32x4  __attribute__((ext_vector_type(4)));
typedef short bf16x8 __attribute__((ext_vector_type(8)));
typedef short bf16x4 __attribute__((ext_vector_type(4)));

#define MFMA(a, b, c) __builtin_amdgcn_mfma_f32_16x16x32_bf16(a, b, c, 0, 0, 0)

__device__ __forceinline__ short f2bf(float v) {
    __hip_bfloat16 b = __float2bfloat16(v);
    return __builtin_bit_cast(short, b);
}
__device__ __forceinline__ float bf2f(short s) {
    unsigned u = ((unsigned)(unsigned short)s) << 16;
    return __builtin_bit_cast(float, u);
}

// k-map for ALL A/B fragments: kappa(g,j) = j<4 ? 4g+j : 16+4g+(j-4)
// ---------------------------------------------------------------------------
// Prep: weights -> bf16 fragment order (verified rounds 2-5).
//   W0a: frag 0..15 (ks*8+nt)   W0b: 16..23 (k2*2+ot)
//   W1a: 24..47 (ks*8+nt)       W1b: 48..55 (k2*2+ot)
// ---------------------------------------------------------------------------
__global__ __launch_bounds__(64) void prep_kernel(
    const float* __restrict__ W0a, const float* __restrict__ W0b,
    const float* __restrict__ W1a, const float* __restrict__ W1b,
    bf16x8* __restrict__ frag)
{
    const int fid = blockIdx.x, l = threadIdx.x, c = l & 15, g = l >> 4;
    const float* W; int N, ks, nt;
    if (fid < 16)      { W = W0a; N = 128; ks = fid >> 3;        nt = fid & 7; }
    else if (fid < 24) { W = W0b; N = 32;  ks = (fid - 16) >> 1; nt = (fid - 16) & 1; }
    else if (fid < 48) { W = W1a; N = 128; ks = (fid - 24) >> 3; nt = (fid - 24) & 7; }
    else               { W = W1b; N = 32;  ks = (fid - 48) >> 1; nt = (fid - 48) & 1; }
    bf16x8 f;
    #pragma unroll
    for (int j = 0; j < 8; ++j) {
        const int k = 32 * ks + ((j < 4) ? (4 * g + j) : (16 + 4 * g + (j - 4)));
        f[j] = f2bf(W[k * N + 16 * nt + c]);
    }
    frag[fid * 64 + l] = f;
}

// ---------------------------------------------------------------------------
// Fused kernel, phase-grouped over 2 chunks (512 rows/block):
//   scan both chunks -> per-row sfull table in LDS
//   phase A: wa0/wb0 REGISTER-RESIDENT, 8 tiles + p-tile -> out0 in LDS (bf16)
//   phase B: wa1/wb1 REGISTER-RESIDENT, 8 tiles; gather via sfull; blend; out
// Inner loops are pure-register MFMA (no memory on the critical path).
// ---------------------------------------------------------------------------
__global__ __launch_bounds__(256, 2) void fused_kernel(
    const float* __restrict__ x, const int* __restrict__ topk,
    const float* __restrict__ wts,
    const float* __restrict__ b0a, const float* __restrict__ b0b,
    const float* __restrict__ b1a, const float* __restrict__ b1b,
    const bf16x8* __restrict__ frag,
    float* __restrict__ out)
{
    const int b = blockIdx.x;
    const int bb = b * RPB;
    const int tid = threadIdx.x, wv = tid >> 6, l = tid & 63, c = l & 15, g = l >> 4;

    __shared__ __align__(16) short out0_lds[513 * LSTRIDE];  // 36.9 KB
    __shared__ unsigned short sfull_lds[512];                // 1 KB
    __shared__ int wtot[2][4];

    // --- scans for both chunks: wave-local inclusive cummax of (m0 ? row : 0) ---
    int s01[2];
    #pragma unroll
    for (int ci = 0; ci < 2; ++ci) {
        const int row = bb + ci * 256 + tid;
        const int2 tk = ((const int2*)topk)[row];
        const bool m0 = (tk.x == 0) || (tk.y == 0);
        int s = m0 ? row : 0;
        #pragma unroll
        for (int off = 1; off < 64; off <<= 1) {
            int u = __shfl_up(s, off, 64);
            if (l >= off) s = max(s, u);
        }
        if (l == 63) wtot[ci][wv] = s;
        s01[ci] = s;
    }

    // --- global p: last mask0 row < bb (input-only backward ballot scan) ---
    int p = 0;
    for (int base = bb - 64; base >= 0; base -= 64) {
        const int2 tkq = ((const int2*)topk)[base + l];
        const bool mm = (tkq.x == 0) || (tkq.y == 0);
        const unsigned long long bal = __ballot(mm);
        if (bal) { p = base + 63 - __clzll(bal); break; }
    }
    const int2 tkp = ((const int2*)topk)[p];
    const bool m0p = (tkp.x == 0) || (tkp.y == 0);

    // --- x prologue: 8 tiles (tile = ci*4 + rt), the only x read ---
    bf16x8 xf[8][2];
    #pragma unroll
    for (int tile = 0; tile < 8; ++tile) {
        const int slot = (tile >> 2) * 256 + wv * 64 + (tile & 3) * 16 + c;
        const float* xr = x + (size_t)(bb + slot) * 64;
        #pragma unroll
        for (int ks = 0; ks < 2; ++ks) {
            f32x4 a  = *(const f32x4*)(xr + 32 * ks + 4 * g);
            f32x4 b2 = *(const f32x4*)(xr + 32 * ks + 16 + 4 * g);
            #pragma unroll
            for (int j = 0; j < 4; ++j) { xf[tile][ks][j] = f2bf(a[j]); xf[tile][ks][4 + j] = f2bf(b2[j]); }
        }
    }
    bf16x8 xfp[2];
    if (wv == 3) {                     // wave 3 owns the p-tile
        const float* xp = x + (size_t)p * 64;
        #pragma unroll
        for (int ks = 0; ks < 2; ++ks) {
            f32x4 a  = *(const f32x4*)(xp + 32 * ks + 4 * g);
            f32x4 b2 = *(const f32x4*)(xp + 32 * ks + 16 + 4 * g);
            #pragma unroll
            for (int j = 0; j < 4; ++j) { xfp[ks][j] = f2bf(a[j]); xfp[ks][4 + j] = f2bf(b2[j]); }
        }
    }

    __syncthreads();   // barrier 1: wtot visible

    // --- per-row global cummax -> sfull table (rel+1; 0 => use p slot 512) ---
    {
        int pre0 = 0, all0 = 0;
        #pragma unroll
        for (int w2 = 0; w2 < 4; ++w2) {
            const int v = wtot[0][w2];
            if (w2 < wv) pre0 = max(pre0, v);
            all0 = max(all0, v);
        }
        int pre1 = all0;
        #pragma unroll
        for (int w2 = 0; w2 < 4; ++w2)
            if (w2 < wv) pre1 = max(pre1, wtot[1][w2]);
        const int sf0 = max(pre0, s01[0]);
        const int sf1 = max(pre1, s01[1]);
        sfull_lds[tid]       = sf0 ? (unsigned short)(sf0 - bb + 1) : 0;
        sfull_lds[256 + tid] = sf1 ? (unsigned short)(sf1 - bb + 1) : 0;
    }

    // --- phase A weights: register-resident (96 VGPR) ---
    bf16x8 wa0[2][8], wb0[4][2];
    #pragma unroll
    for (int ks = 0; ks < 2; ++ks)
        #pragma unroll
        for (int nt = 0; nt < 8; ++nt) wa0[ks][nt] = frag[(ks * 8 + nt) * 64 + l];
    #pragma unroll
    for (int k2 = 0; k2 < 4; ++k2)
        #pragma unroll
        for (int ot = 0; ot < 2; ++ot) wb0[k2][ot] = frag[(16 + k2 * 2 + ot) * 64 + l];
    f32x4 b0br[2];
    b0br[0] = *(const f32x4*)(b0b + 4 * g);
    b0br[1] = *(const f32x4*)(b0b + 16 + 4 * g);

    // --- phase A: 8 tiles, pure-register inner loops ---
    #pragma unroll
    for (int tile = 0; tile < 8; ++tile) {
        const int slot = (tile >> 2) * 256 + wv * 64 + (tile & 3) * 16 + c;
        f32x4 acc2[2] = { b0br[0], b0br[1] };
        #pragma unroll
        for (int h = 0; h < 2; ++h) {           // nt-halves keep transients small
            f32x4 a1[4];
            #pragma unroll
            for (int q = 0; q < 4; ++q) a1[q] = *(const f32x4*)(b0a + 16 * (4 * h + q) + 4 * g);
            #pragma unroll
            for (int ks = 0; ks < 2; ++ks)
                #pragma unroll
                for (int q = 0; q < 4; ++q) a1[q] = MFMA(wa0[ks][4 * h + q], xf[tile][ks], a1[q]);
            #pragma unroll
            for (int m = 0; m < 2; ++m) {       // k2 = 2h+m
                bf16x8 hf;
                #pragma unroll
                for (int j = 0; j < 8; ++j)
                    hf[j] = f2bf(fmaxf(a1[2 * m + (j >> 2)][j & 3], 0.0f));
                acc2[0] = MFMA(wb0[2 * h + m][0], hf, acc2[0]);
                acc2[1] = MFMA(wb0[2 * h + m][1], hf, acc2[1]);
            }
        }
        const int2 tk = ((const int2*)topk)[bb + slot];
        const bool m0 = (tk.x == 0) || (tk.y == 0);
        #pragma unroll
        for (int ot = 0; ot < 2; ++ot) {
            bf16x4 v;
            #pragma unroll
            for (int j = 0; j < 4; ++j) v[j] = f2bf(m0 ? acc2[ot][j] : 0.0f);
            *(bf16x4*)(&out0_lds[slot * LSTRIDE + 16 * ot + 4 * g]) = v;
        }
    }

    // --- wave 3: p-row tile -> slot 512 ---
    if (wv == 3) {
        f32x4 acc2[2] = { b0br[0], b0br[1] };
        #pragma unroll
        for (int h = 0; h < 2; ++h) {
            f32x4 a1[4];
            #pragma unroll
            for (int q = 0; q < 4; ++q) a1[q] = *(const f32x4*)(b0a + 16 * (4 * h + q) + 4 * g);
            #pragma unroll
            for (int ks = 0; ks < 2; ++ks)
                #pragma unroll
                for (int q = 0; q < 4; ++q) a1[q] = MFMA(wa0[ks][4 * h + q], xfp[ks], a1[q]);
            #pragma unroll
            for (int m = 0; m < 2; ++m) {
                bf16x8 hf;
                #pragma unroll
                for (int j = 0; j < 8; ++j)
                    hf[j] = f2bf(fmaxf(a1[2 * m + (j >> 2)][j & 3], 0.0f));
                acc2[0] = MFMA(wb0[2 * h + m][0], hf, acc2[0]);
                acc2[1] = MFMA(wb0[2 * h + m][1], hf, acc2[1]);
            }
        }
        if (c == 0) {
            #pragma unroll
            for (int ot = 0; ot < 2; ++ot) {
                bf16x4 v;
                #pragma unroll
                for (int j = 0; j < 4; ++j) v[j] = f2bf(m0p ? acc2[ot][j] : 0.0f);
                *(bf16x4*)(&out0_lds[512 * LSTRIDE + 16 * ot + 4 * g]) = v;
            }
        }
    }

    __syncthreads();   // barrier 2: out0 + sfull tables complete

    // --- phase B weights: register-resident (128 VGPR; wa0/wb0 dead) ---
    bf16x8 wa1[3][8], wb1[4][2];
    #pragma unroll
    for (int ks = 0; ks < 3; ++ks)
        #pragma unroll
        for (int nt = 0; nt < 8; ++nt) wa1[ks][nt] = frag[(24 + ks * 8 + nt) * 64 + l];
    #pragma unroll
    for (int k2 = 0; k2 < 4; ++k2)
        #pragma unroll
        for (int ot = 0; ot < 2; ++ot) wb1[k2][ot] = frag[(48 + k2 * 2 + ot) * 64 + l];
    f32x4 b1br[2];
    b1br[0] = *(const f32x4*)(b1b + 4 * g);
    b1br[1] = *(const f32x4*)(b1b + 16 + 4 * g);

    // --- phase B: 8 tiles ---
    #pragma unroll
    for (int tile = 0; tile < 8; ++tile) {
        const int slot = (tile >> 2) * 256 + wv * 64 + (tile & 3) * 16 + c;
        const int row = bb + slot;

        const unsigned v = sfull_lds[slot];
        const int gslot = v ? (int)v - 1 : 512;
        bf16x8 xf2;
        {
            const short* fr = &out0_lds[gslot * LSTRIDE];
            bf16x4 fa = *(const bf16x4*)(fr + 4 * g);
            bf16x4 fb = *(const bf16x4*)(fr + 16 + 4 * g);
            #pragma unroll
            for (int j = 0; j < 4; ++j) { xf2[j] = fa[j]; xf2[4 + j] = fb[j]; }
        }

        f32x4 acc2[2] = { b1br[0], b1br[1] };
        #pragma unroll
        for (int h = 0; h < 2; ++h) {
            f32x4 a1[4];
            #pragma unroll
            for (int q = 0; q < 4; ++q) a1[q] = *(const f32x4*)(b1a + 16 * (4 * h + q) + 4 * g);
            #pragma unroll
            for (int ks = 0; ks < 2; ++ks)
                #pragma unroll
                for (int q = 0; q < 4; ++q) a1[q] = MFMA(wa1[ks][4 * h + q], xf[tile][ks], a1[q]);
            #pragma unroll
            for (int q = 0; q < 4; ++q) a1[q] = MFMA(wa1[2][4 * h + q], xf2, a1[q]);
            #pragma unroll
            for (int m = 0; m < 2; ++m) {
                bf16x8 hf;
                #pragma unroll
                for (int j = 0; j < 8; ++j)
                    hf[j] = f2bf(fmaxf(a1[2 * m + (j >> 2)][j & 3], 0.0f));
                acc2[0] = MFMA(wb1[2 * h + m][0], hf, acc2[0]);
                acc2[1] = MFMA(wb1[2 * h + m][1], hf, acc2[1]);
            }
        }

        const int2 tk = ((const int2*)topk)[row];
        const bool m1 = (tk.x == 1) || (tk.y == 1);
        const float w  = wts[(size_t)row * 2];
        const float wc = 1.0f - w;
        #pragma unroll
        for (int ot = 0; ot < 2; ++ot) {
            bf16x4 oa = *(const bf16x4*)(&out0_lds[slot * LSTRIDE + 16 * ot + 4 * g]);
            f32x4 r;
            #pragma unroll
            for (int j = 0; j < 4; ++j) {
                const float e1 = m1 ? acc2[ot][j] : 0.0f;
                r[j] = w * bf2f(oa[j]) + wc * e1;
            }
            *(f32x4*)(out + (size_t)row * 32 + 16 * ot + 4 * g) = r;
        }
    }
}

// ---------------------------------------------------------------------------
extern "C" void kernel_launch(void* const* d_in, const int* in_sizes, int n_in,
                              void* d_out, int out_size, void* d_ws, size_t ws_size,
                              hipStream_t stream)
{
    const float* x    = (const float*)d_in[0];
    const int*   topk = (const int*)  d_in[1];
    const float* wts  = (const float*)d_in[2];
    const float* W0a  = (const float*)d_in[3];
    const float* b0a  = (const float*)d_in[4];
    const float* W0b  = (const float*)d_in[5];
    const float* b0b  = (const float*)d_in[6];
    const float* W1a  = (const float*)d_in[7];
    const float* b1a  = (const float*)d_in[8];
    const float* W1b  = (const float*)d_in[9];
    const float* b1b  = (const float*)d_in[10];
    float* out = (float*)d_out;

    bf16x8* frag = (bf16x8*)d_ws;   // 56 KiB

    prep_kernel<<<dim3(56), dim3(64), 0, stream>>>(W0a, W0b, W1a, W1b, frag);
    fused_kernel<<<dim3(NBLK), dim3(256), 0, stream>>>(
        x, topk, wts, b0a, b0b, b1a, b1b, frag, out);
}

// Round 7
// 122.939 us; speedup vs baseline: 1.3142x; 1.3142x over previous
//
#include <hip/hip_runtime.h>
#include <hip/hip_bf16.h>

#define TROWS 1048576
#define RPB   256                    // rows per block (chunk)
#define NCHUNK (TROWS / RPB)         // 4096
#define LSTRIDE 36                   // out0 LDS row stride in shorts (72 B)

typedef float f32x4  __attribute__((ext_vector_type(4)));
typedef short bf16x8 __attribute__((ext_vector_type(8)));
typedef short bf16x4 __attribute__((ext_vector_type(4)));

#define MFMA(a, b, c) __builtin_amdgcn_mfma_f32_16x16x32_bf16(a, b, c, 0, 0, 0)

__device__ __forceinline__ short f2bf(float v) {
    __hip_bfloat16 b = __float2bfloat16(v);
    return __builtin_bit_cast(short, b);
}
__device__ __forceinline__ float bf2f(short s) {
    unsigned u = ((unsigned)(unsigned short)s) << 16;
    return __builtin_bit_cast(float, u);
}

// k-map for ALL A/B fragments: kappa(g,j) = j<4 ? 4g+j : 16+4g+(j-4)
// ---------------------------------------------------------------------------
// Prep: weights -> bf16 fragment order (verified rounds 2-6).
//   W0a: frag 0..15 (ks*8+nt)   W0b: 16..23 (k2*2+ot)
//   W1a: 24..47 (ks*8+nt)       W1b: 48..55 (k2*2+ot)
// ---------------------------------------------------------------------------
__global__ __launch_bounds__(64) void prep_kernel(
    const float* __restrict__ W0a, const float* __restrict__ W0b,
    const float* __restrict__ W1a, const float* __restrict__ W1b,
    bf16x8* __restrict__ frag)
{
    const int fid = blockIdx.x, l = threadIdx.x, c = l & 15, g = l >> 4;
    const float* W; int N, ks, nt;
    if (fid < 16)      { W = W0a; N = 128; ks = fid >> 3;        nt = fid & 7; }
    else if (fid < 24) { W = W0b; N = 32;  ks = (fid - 16) >> 1; nt = (fid - 16) & 1; }
    else if (fid < 48) { W = W1a; N = 128; ks = (fid - 24) >> 3; nt = (fid - 24) & 7; }
    else               { W = W1b; N = 32;  ks = (fid - 48) >> 1; nt = (fid - 48) & 1; }
    bf16x8 f;
    #pragma unroll
    for (int j = 0; j < 8; ++j) {
        const int k = 32 * ks + ((j < 4) ? (4 * g + j) : (16 + 4 * g + (j - 4)));
        f[j] = f2bf(W[k * N + 16 * nt + c]);
    }
    frag[fid * 64 + l] = f;
}

// ---------------------------------------------------------------------------
// Fused kernel: weight frags staged in LDS (two-phase, 32KB union), shared by
// all 4 waves. Inner loops: ds_read frags (k2-outer, amortized over 4 tiles),
// pure-register MFMA. Scan/p-row/gather identical to verified r5.
// ---------------------------------------------------------------------------
__global__ __launch_bounds__(256, 3) void fused_kernel(
    const float* __restrict__ x, const int* __restrict__ topk,
    const float* __restrict__ wts,
    const float* __restrict__ b0a, const float* __restrict__ b0b,
    const float* __restrict__ b1a, const float* __restrict__ b1b,
    const bf16x8* __restrict__ frag,
    float* __restrict__ out)
{
    const int b = blockIdx.x;
    const int bb = b * RPB;
    const int tid = threadIdx.x, wv = tid >> 6, l = tid & 63, c = l & 15, g = l >> 4;

    __shared__ __align__(16) short frag_lds[32 * 64 * 8];    // 32 KB (W0: 24KB, then W1: 32KB)
    __shared__ __align__(16) short out0_lds[257 * LSTRIDE];  // 18.5 KB
    __shared__ int wtot[4];

    // frag read from LDS: local frag id fl, lane l
    #define LDSF(fl) (*(const bf16x8*)&frag_lds[(((fl) * 64) + l) * 8])

    // --- stage W0 frags (global fid 0..23 -> local 0..23): 24KB, 6 x 16B/thread ---
    #pragma unroll
    for (int i = 0; i < 6; ++i) {
        const int e = tid + i * 256;      // e < 1536
        *(f32x4*)&frag_lds[e * 8] = *(const f32x4*)&frag[e];
    }

    // --- own-row inclusive wave cummax of (mask0 ? t : 0) ---
    const int t = bb + tid;
    const int2 tko = ((const int2*)topk)[t];
    const bool m0o = (tko.x == 0) || (tko.y == 0);
    int s = m0o ? t : 0;
    #pragma unroll
    for (int off = 1; off < 64; off <<= 1) {
        int u = __shfl_up(s, off, 64);
        if (l >= off) s = max(s, u);
    }
    if (l == 63) wtot[wv] = s;

    // --- backward scan for p = last mask0 row < bb (input-only) ---
    int p = 0;
    for (int base = bb - 64; base >= 0; base -= 64) {
        const int2 tkq = ((const int2*)topk)[base + l];
        const bool mm = (tkq.x == 0) || (tkq.y == 0);
        const unsigned long long bal = __ballot(mm);
        if (bal) { p = base + 63 - __clzll(bal); break; }
    }
    const int2 tkp = ((const int2*)topk)[p];
    const bool m0p = (tkp.x == 0) || (tkp.y == 0);

    // --- x fragments: own 4 tiles (+ p-row on wave 3), the only x reads ---
    bf16x8 xf[4][2];
    #pragma unroll
    for (int rt = 0; rt < 4; ++rt) {
        const int row = bb + wv * 64 + rt * 16 + c;
        const float* xr = x + (size_t)row * 64;
        #pragma unroll
        for (int ks = 0; ks < 2; ++ks) {
            f32x4 a  = *(const f32x4*)(xr + 32 * ks + 4 * g);
            f32x4 b2 = *(const f32x4*)(xr + 32 * ks + 16 + 4 * g);
            #pragma unroll
            for (int j = 0; j < 4; ++j) { xf[rt][ks][j] = f2bf(a[j]); xf[rt][ks][4 + j] = f2bf(b2[j]); }
        }
    }
    bf16x8 xfp[2];
    if (wv == 3) {
        const float* xp = x + (size_t)p * 64;
        #pragma unroll
        for (int ks = 0; ks < 2; ++ks) {
            f32x4 a  = *(const f32x4*)(xp + 32 * ks + 4 * g);
            f32x4 b2 = *(const f32x4*)(xp + 32 * ks + 16 + 4 * g);
            #pragma unroll
            for (int j = 0; j < 4; ++j) { xfp[ks][j] = f2bf(a[j]); xfp[ks][4 + j] = f2bf(b2[j]); }
        }
    }

    __syncthreads();   // B1: W0 frags staged; wtot visible

    // --- per-row global inclusive cummax (kept in reg) ---
    int pre = 0;
    #pragma unroll
    for (int w2 = 0; w2 < 4; ++w2)
        if (w2 < wv) pre = max(pre, wtot[w2]);
    const int s_full = max(pre, s);

    // ---- phase A: MLP0, k2-outer (frags ds_read once, 4 tiles share) ----
    f32x4 acc2a[4][2];
    {
        f32x4 bi0 = *(const f32x4*)(b0b + 4 * g);
        f32x4 bi1 = *(const f32x4*)(b0b + 16 + 4 * g);
        #pragma unroll
        for (int rt = 0; rt < 4; ++rt) { acc2a[rt][0] = bi0; acc2a[rt][1] = bi1; }
    }
    #pragma unroll
    for (int k2 = 0; k2 < 4; ++k2) {
        const bf16x8 fa00 = LDSF(0 * 8 + 2 * k2 + 0);
        const bf16x8 fa01 = LDSF(0 * 8 + 2 * k2 + 1);
        const bf16x8 fa10 = LDSF(1 * 8 + 2 * k2 + 0);
        const bf16x8 fa11 = LDSF(1 * 8 + 2 * k2 + 1);
        const bf16x8 fb0  = LDSF(16 + 2 * k2 + 0);
        const bf16x8 fb1  = LDSF(16 + 2 * k2 + 1);
        const f32x4 bi0 = *(const f32x4*)(b0a + 16 * (2 * k2 + 0) + 4 * g);
        const f32x4 bi1 = *(const f32x4*)(b0a + 16 * (2 * k2 + 1) + 4 * g);
        #pragma unroll
        for (int rt = 0; rt < 4; ++rt) {
            f32x4 a10 = bi0, a11 = bi1;
            a10 = MFMA(fa00, xf[rt][0], a10);
            a10 = MFMA(fa10, xf[rt][1], a10);
            a11 = MFMA(fa01, xf[rt][0], a11);
            a11 = MFMA(fa11, xf[rt][1], a11);
            bf16x8 hf;
            #pragma unroll
            for (int j = 0; j < 8; ++j)
                hf[j] = f2bf(fmaxf((j < 4 ? a10 : a11)[j & 3], 0.0f));
            acc2a[rt][0] = MFMA(fb0, hf, acc2a[rt][0]);
            acc2a[rt][1] = MFMA(fb1, hf, acc2a[rt][1]);
        }
    }

    // --- store own tiles (masked) to out0 LDS ---
    #pragma unroll
    for (int rt = 0; rt < 4; ++rt) {
        const int slot = wv * 64 + rt * 16 + c;
        const int2 tk = ((const int2*)topk)[bb + slot];
        const bool m0 = (tk.x == 0) || (tk.y == 0);
        #pragma unroll
        for (int ot = 0; ot < 2; ++ot) {
            bf16x4 v;
            #pragma unroll
            for (int j = 0; j < 4; ++j) v[j] = f2bf(m0 ? acc2a[rt][ot][j] : 0.0f);
            *(bf16x4*)(&out0_lds[slot * LSTRIDE + 16 * ot + 4 * g]) = v;
        }
    }

    // --- wave 3: p-row tile -> slot 256 ---
    if (wv == 3) {
        f32x4 accp[2];
        accp[0] = *(const f32x4*)(b0b + 4 * g);
        accp[1] = *(const f32x4*)(b0b + 16 + 4 * g);
        #pragma unroll
        for (int k2 = 0; k2 < 4; ++k2) {
            const bf16x8 fa00 = LDSF(0 * 8 + 2 * k2 + 0);
            const bf16x8 fa01 = LDSF(0 * 8 + 2 * k2 + 1);
            const bf16x8 fa10 = LDSF(1 * 8 + 2 * k2 + 0);
            const bf16x8 fa11 = LDSF(1 * 8 + 2 * k2 + 1);
            const bf16x8 fb0  = LDSF(16 + 2 * k2 + 0);
            const bf16x8 fb1  = LDSF(16 + 2 * k2 + 1);
            f32x4 a10 = *(const f32x4*)(b0a + 16 * (2 * k2 + 0) + 4 * g);
            f32x4 a11 = *(const f32x4*)(b0a + 16 * (2 * k2 + 1) + 4 * g);
            a10 = MFMA(fa00, xfp[0], a10);
            a10 = MFMA(fa10, xfp[1], a10);
            a11 = MFMA(fa01, xfp[0], a11);
            a11 = MFMA(fa11, xfp[1], a11);
            bf16x8 hf;
            #pragma unroll
            for (int j = 0; j < 8; ++j)
                hf[j] = f2bf(fmaxf((j < 4 ? a10 : a11)[j & 3], 0.0f));
            accp[0] = MFMA(fb0, hf, accp[0]);
            accp[1] = MFMA(fb1, hf, accp[1]);
        }
        if (c == 0) {
            #pragma unroll
            for (int ot = 0; ot < 2; ++ot) {
                bf16x4 v;
                #pragma unroll
                for (int j = 0; j < 4; ++j) v[j] = f2bf(m0p ? accp[ot][j] : 0.0f);
                *(bf16x4*)(&out0_lds[256 * LSTRIDE + 16 * ot + 4 * g]) = v;
            }
        }
    }

    __syncthreads();   // B2: out0 complete; all W0 frag reads done

    // --- stage W1 frags (global fid 24..55 -> local 0..31): 32KB ---
    #pragma unroll
    for (int i = 0; i < 8; ++i) {
        const int e = tid + i * 256;      // e < 2048
        *(f32x4*)&frag_lds[e * 8] = *(const f32x4*)&frag[24 * 64 + e];
    }

    __syncthreads();   // B3: W1 frags staged

    // --- gather filled frags via s_full ---
    bf16x8 xf2[4];
    #pragma unroll
    for (int rt = 0; rt < 4; ++rt) {
        const int sF = __shfl(s_full, rt * 16 + c, 64);
        const int slot = (sF > 0) ? (sF - bb) : 256;
        const short* fr = &out0_lds[slot * LSTRIDE];
        bf16x4 fa_ = *(const bf16x4*)(fr + 4 * g);
        bf16x4 fb_ = *(const bf16x4*)(fr + 16 + 4 * g);
        #pragma unroll
        for (int j = 0; j < 4; ++j) { xf2[rt][j] = fa_[j]; xf2[rt][4 + j] = fb_[j]; }
    }

    // ---- phase B: MLP1, k2-outer ----
    f32x4 acc2b[4][2];
    {
        f32x4 bi0 = *(const f32x4*)(b1b + 4 * g);
        f32x4 bi1 = *(const f32x4*)(b1b + 16 + 4 * g);
        #pragma unroll
        for (int rt = 0; rt < 4; ++rt) { acc2b[rt][0] = bi0; acc2b[rt][1] = bi1; }
    }
    #pragma unroll
    for (int k2 = 0; k2 < 4; ++k2) {
        const bf16x8 fa00 = LDSF(0 * 8 + 2 * k2 + 0);   // W1a local 0..23
        const bf16x8 fa01 = LDSF(0 * 8 + 2 * k2 + 1);
        const bf16x8 fa10 = LDSF(1 * 8 + 2 * k2 + 0);
        const bf16x8 fa11 = LDSF(1 * 8 + 2 * k2 + 1);
        const bf16x8 fa20 = LDSF(2 * 8 + 2 * k2 + 0);
        const bf16x8 fa21 = LDSF(2 * 8 + 2 * k2 + 1);
        const bf16x8 fb0  = LDSF(24 + 2 * k2 + 0);      // W1b local 24..31
        const bf16x8 fb1  = LDSF(24 + 2 * k2 + 1);
        const f32x4 bi0 = *(const f32x4*)(b1a + 16 * (2 * k2 + 0) + 4 * g);
        const f32x4 bi1 = *(const f32x4*)(b1a + 16 * (2 * k2 + 1) + 4 * g);
        #pragma unroll
        for (int rt = 0; rt < 4; ++rt) {
            f32x4 a10 = bi0, a11 = bi1;
            a10 = MFMA(fa00, xf[rt][0], a10);
            a10 = MFMA(fa10, xf[rt][1], a10);
            a10 = MFMA(fa20, xf2[rt], a10);
            a11 = MFMA(fa01, xf[rt][0], a11);
            a11 = MFMA(fa11, xf[rt][1], a11);
            a11 = MFMA(fa21, xf2[rt], a11);
            bf16x8 hf;
            #pragma unroll
            for (int j = 0; j < 8; ++j)
                hf[j] = f2bf(fmaxf((j < 4 ? a10 : a11)[j & 3], 0.0f));
            acc2b[rt][0] = MFMA(fb0, hf, acc2b[rt][0]);
            acc2b[rt][1] = MFMA(fb1, hf, acc2b[rt][1]);
        }
    }

    // --- blend + store ---
    #pragma unroll
    for (int rt = 0; rt < 4; ++rt) {
        const int slot = wv * 64 + rt * 16 + c;
        const int row = bb + slot;
        const int2 tk = ((const int2*)topk)[row];
        const bool m1 = (tk.x == 1) || (tk.y == 1);
        const float w  = wts[(size_t)row * 2];
        const float wc = 1.0f - w;
        #pragma unroll
        for (int ot = 0; ot < 2; ++ot) {
            bf16x4 oa = *(const bf16x4*)(&out0_lds[slot * LSTRIDE + 16 * ot + 4 * g]);
            f32x4 r;
            #pragma unroll
            for (int j = 0; j < 4; ++j) {
                const float e1 = m1 ? acc2b[rt][ot][j] : 0.0f;
                r[j] = w * bf2f(oa[j]) + wc * e1;
            }
            *(f32x4*)(out + (size_t)row * 32 + 16 * ot + 4 * g) = r;
        }
    }
    #undef LDSF
}

// ---------------------------------------------------------------------------
extern "C" void kernel_launch(void* const* d_in, const int* in_sizes, int n_in,
                              void* d_out, int out_size, void* d_ws, size_t ws_size,
                              hipStream_t stream)
{
    const float* x    = (const float*)d_in[0];
    const int*   topk = (const int*)  d_in[1];
    const float* wts  = (const float*)d_in[2];
    const float* W0a  = (const float*)d_in[3];
    const float* b0a  = (const float*)d_in[4];
    const float* W0b  = (const float*)d_in[5];
    const float* b0b  = (const float*)d_in[6];
    const float* W1a  = (const float*)d_in[7];
    const float* b1a  = (const float*)d_in[8];
    const float* W1b  = (const float*)d_in[9];
    const float* b1b  = (const float*)d_in[10];
    float* out = (float*)d_out;

    bf16x8* frag = (bf16x8*)d_ws;   // 56 KiB

    prep_kernel<<<dim3(56), dim3(64), 0, stream>>>(W0a, W0b, W1a, W1b, frag);
    fused_kernel<<<dim3(NCHUNK), dim3(256), 0, stream>>>(
        x, topk, wts, b0a, b0b, b1a, b1b, frag, out);
}